// Round 13
// baseline (1280.028 us; speedup 1.0000x reference)
//
#include <hip/hip_runtime.h>
#include <stdint.h>

#define B_    16
#define N_    4096
#define CPTS  64
#define S_    1024
#define K_    32

typedef __bf16 bf16x8 __attribute__((ext_vector_type(8)));
typedef float  f32x4  __attribute__((ext_vector_type(4)));
typedef unsigned short ushort8 __attribute__((ext_vector_type(8)));

__device__ __forceinline__ float fmul_(float a, float b){ return __fmul_rn(a,b); }
__device__ __forceinline__ float fadd_(float a, float b){ return __fadd_rn(a,b); }
__device__ __forceinline__ float fsub_(float a, float b){ return __fsub_rn(a,b); }

__device__ __forceinline__ unsigned short f2bf(float f){
  unsigned u = __float_as_uint(f);
  unsigned r = (u + 0x7FFFu + ((u >> 16) & 1u)) >> 16;
  return (unsigned short)r;
}

__device__ __forceinline__ f32x4 mfma_16x16x32(bf16x8 a, bf16x8 b, f32x4 c){
  return __builtin_amdgcn_mfma_f32_16x16x32_bf16(a, b, c, 0, 0, 0);
}

__device__ __forceinline__ unsigned long long umin64(unsigned long long a, unsigned long long b){
  return b < a ? b : a;
}
__device__ __forceinline__ unsigned long long umax64(unsigned long long a, unsigned long long b){
  return a < b ? b : a;
}

template<int CTRL>
__device__ __forceinline__ unsigned dppmove(unsigned v){
  return (unsigned)__builtin_amdgcn_update_dpp((int)v, (int)v, CTRL, 0xF, 0xF, false);
}
__device__ __forceinline__ unsigned wave_umax_dpp(unsigned v){
  unsigned t;
  t = dppmove<0x111>(v); v = v > t ? v : t;
  t = dppmove<0x112>(v); v = v > t ? v : t;
  t = dppmove<0x114>(v); v = v > t ? v : t;
  t = dppmove<0x118>(v); v = v > t ? v : t;
  t = dppmove<0x142>(v); v = v > t ? v : t;
  t = dppmove<0x143>(v); v = v > t ? v : t;
  return (unsigned)__builtin_amdgcn_readlane((int)v, 63);
}
__device__ __forceinline__ unsigned wave_umin_dpp(unsigned v){
  unsigned t;
  t = dppmove<0x111>(v); v = v < t ? v : t;
  t = dppmove<0x112>(v); v = v < t ? v : t;
  t = dppmove<0x114>(v); v = v < t ? v : t;
  t = dppmove<0x118>(v); v = v < t ? v : t;
  t = dppmove<0x142>(v); v = v < t ? v : t;
  t = dppmove<0x143>(v); v = v < t ? v : t;
  return (unsigned)__builtin_amdgcn_readlane((int)v, 63);
}

// ---------------------------------------------------------------------------
// FPS: one block per batch, 256 threads, 16 pts/thread (round-10 core).
// Speculative winner-coord prefetch: after the scan each lane reads
// lp[bidx] (its own candidate) while the DPP chains run; the unique winner
// lane publishes coords to wx alongside wc. Post-barrier: wc+wx read in one
// lgkm wait, coords selected via the SAME u64 compares (~idx unique) — the
// dependent lp[far] read is gone from the serial chain.
// ---------------------------------------------------------------------------
__global__ __launch_bounds__(256) void fps_kernel(const float* __restrict__ xyz,
                                                  float* __restrict__ out_newxyz,
                                                  float* __restrict__ stats)
{
  const int b   = blockIdx.x;
  const int tid = threadIdx.x;
  const int wave = tid >> 6;
  __shared__ float4 lp[N_];
  __shared__ unsigned long long wc[2][4];
  __shared__ float4 wx[2][4];
  __shared__ int fhist[S_ + 1];

  // zero stats: 6*8192 floats = 12288 float4, 16 blocks x 256 thr x 3 each
  {
    float4* s4 = (float4*)stats;
    const int base = (b*256 + tid)*3;
    const float4 z = make_float4(0.f,0.f,0.f,0.f);
    s4[base+0] = z; s4[base+1] = z; s4[base+2] = z;
  }

  const float* xb = xyz + (size_t)b * (N_*3);
  float px[16], py[16], pz[16], dmin[16];
#pragma unroll
  for (int i = 0; i < 16; ++i) {
    int n = i*256 + tid;
    float x = xb[n*3+0], y = xb[n*3+1], z = xb[n*3+2];
    lp[n] = make_float4(x,y,z,0.0f);
    px[i]=x; py[i]=y; pz[i]=z;
    dmin[i] = INFINITY;
  }
  if (tid == 0) fhist[0] = 0;
  float cx = xb[0], cy = xb[1], cz = xb[2];   // initial centroid = point 0
  __syncthreads();

  for (int step = 0; step < S_; ++step) {
    float bv = -1.0f; unsigned bidx = 0;
#pragma unroll
    for (int i = 0; i < 16; ++i) {
      float dx = fsub_(px[i],cx), dy = fsub_(py[i],cy), dz = fsub_(pz[i],cz);
      float d  = fadd_(fadd_(fmul_(dx,dx),fmul_(dy,dy)),fmul_(dz,dz));
      float dm = fminf(dmin[i], d);
      dmin[i] = dm;
      bool gt = dm > bv;                      // strict >: lowest i wins ties
      bv   = gt ? dm : bv;
      bidx = gt ? (unsigned)(i*256 + tid) : bidx;
    }
    float4 myc = lp[bidx];                    // speculative: overlaps DPP chains
    unsigned bvb  = __float_as_uint(bv);      // bv>=0 -> bits order-monotone
    unsigned wmax = wave_umax_dpp(bvb);
    unsigned winv = wave_umax_dpp((bvb == wmax) ? ~bidx : 0u);

    int par = step & 1;
    if (~bidx == winv) {                      // unique winner lane of this wave
      wc[par][wave] = ((unsigned long long)wmax << 32) | winv;
      wx[par][wave] = myc;
    }
    __syncthreads();
    unsigned long long c0 = wc[par][0], c1 = wc[par][1];
    unsigned long long c2 = wc[par][2], c3 = wc[par][3];
    float4 x0 = wx[par][0], x1 = wx[par][1], x2 = wx[par][2], x3 = wx[par][3];
    unsigned long long m01 = umax64(c0, c1);
    float4 s01 = (c1 > c0) ? x1 : x0;         // keys distinct (~idx unique)
    unsigned long long m23 = umax64(c2, c3);
    float4 s23 = (c3 > c2) ? x3 : x2;
    bool sel23 = m23 > m01;
    unsigned long long best = sel23 ? m23 : m01;
    float4 selc = sel23 ? s23 : s01;
    cx = selc.x; cy = selc.y; cz = selc.z;
    if (tid == 0) fhist[step + 1] = (int)(~(unsigned)best);
  }
  __syncthreads();

  float* ob = out_newxyz + (size_t)b*S_*3;
#pragma unroll
  for (int j = 0; j < 4; ++j) {
    int s = j*256 + tid;
    float4 p = lp[fhist[s]];
    ob[s*3+0] = p.x; ob[s*3+1] = p.y; ob[s*3+2] = p.z;
  }
}

// ---------------------------------------------------------------------------
// kNN (round-8): wave-per-query, all-VALU extraction (DPP two-phase min).
// ---------------------------------------------------------------------------
#define KNN_REB(G) { \
  if (isw) { \
    if      (jj==0u) sk[(G)*8+0]=0xFFFFFFFFu; else if (jj==1u) sk[(G)*8+1]=0xFFFFFFFFu; \
    else if (jj==2u) sk[(G)*8+2]=0xFFFFFFFFu; else if (jj==3u) sk[(G)*8+3]=0xFFFFFFFFu; \
    else if (jj==4u) sk[(G)*8+4]=0xFFFFFFFFu; else if (jj==5u) sk[(G)*8+5]=0xFFFFFFFFu; \
    else if (jj==6u) sk[(G)*8+6]=0xFFFFFFFFu; else              sk[(G)*8+7]=0xFFFFFFFFu; } \
  { unsigned bk = sk[(G)*8+0]; unsigned bi = (unsigned)(((G)*8+0)*64 + lane); \
    _Pragma("unroll") \
    for (int j2 = 1; j2 < 8; ++j2) { \
      unsigned k2 = sk[(G)*8+j2]; unsigned i2 = (unsigned)(((G)*8+j2)*64 + lane); \
      bool lt = k2 < bk; bk = lt ? k2 : bk; bi = lt ? i2 : bi; } \
    gk[(G)] = bk; gi[(G)] = bi; } }

__global__ __launch_bounds__(256) void knn_kernel(const float* __restrict__ xyz,
                                                  const float* __restrict__ newxyz,
                                                  int* __restrict__ knn)
{
  __shared__ float4 lp[N_];
  const int b     = blockIdx.x >> 6;
  const int chunk = blockIdx.x & 63;
  const float* xb = xyz + (size_t)b * (N_*3);
  for (int e = threadIdx.x; e < N_; e += 256) {
    float x = xb[e*3+0], y = xb[e*3+1], z = xb[e*3+2];
    float d2 = fadd_(fadd_(fmul_(x,x),fmul_(y,y)),fmul_(z,z));
    lp[e] = make_float4(x,y,z,d2);
  }
  __syncthreads();

  const int wave = threadIdx.x >> 6, lane = threadIdx.x & 63;
  for (int qi = 0; qi < 4; ++qi) {
    const int s  = chunk*16 + wave*4 + qi;
    const int fq = b*S_ + s;
    float qx = newxyz[fq*3+0], qy = newxyz[fq*3+1], qz = newxyz[fq*3+2];
    float s2 = fadd_(fadd_(fmul_(qx,qx),fmul_(qy,qy)),fmul_(qz,qz));

    unsigned sk[64];
#pragma unroll
    for (int j = 0; j < 64; ++j) {
      float4 p = lp[j*64 + lane];
      float dot = fadd_(fadd_(fmul_(qx,p.x),fmul_(qy,p.y)),fmul_(qz,p.z));
      float d   = fadd_(fsub_(s2, fmul_(2.0f,dot)), p.w);
      unsigned u = __float_as_uint(d);
      sk[j] = u ^ ((unsigned)((int)u >> 31) | 0x80000000u);
    }
    unsigned gk[8], gi[8];
#pragma unroll
    for (int g = 0; g < 8; ++g) {
      unsigned bk = sk[g*8+0], bi = (unsigned)((g*8+0)*64 + lane);
#pragma unroll
      for (int j = 1; j < 8; ++j) {
        unsigned k2 = sk[g*8+j]; unsigned i2 = (unsigned)((g*8+j)*64 + lane);
        bool lt = k2 < bk; bk = lt ? k2 : bk; bi = lt ? i2 : bi;
      }
      gk[g]=bk; gi[g]=bi;
    }
    int* ko = knn + (size_t)fq * K_;
    for (int it = 0; it < K_; ++it) {
      unsigned long long c0 = ((unsigned long long)gk[0] << 32) | gi[0];
      unsigned long long c1 = ((unsigned long long)gk[1] << 32) | gi[1];
      unsigned long long c2 = ((unsigned long long)gk[2] << 32) | gi[2];
      unsigned long long c3 = ((unsigned long long)gk[3] << 32) | gi[3];
      unsigned long long c4 = ((unsigned long long)gk[4] << 32) | gi[4];
      unsigned long long c5 = ((unsigned long long)gk[5] << 32) | gi[5];
      unsigned long long c6 = ((unsigned long long)gk[6] << 32) | gi[6];
      unsigned long long c7 = ((unsigned long long)gk[7] << 32) | gi[7];
      c0 = umin64(c0,c1); c2 = umin64(c2,c3); c4 = umin64(c4,c5); c6 = umin64(c6,c7);
      c0 = umin64(c0,c2); c4 = umin64(c4,c6);
      unsigned long long cand = umin64(c0,c4);
      unsigned lkey = (unsigned)(cand >> 32);
      unsigned lidx = (unsigned)cand;
      unsigned wkey = wave_umin_dpp(lkey);
      unsigned widx = wave_umin_dpp((lkey == wkey) ? lidx : 0xFFFFFFFFu);
      if (lane == 0) ko[it] = (int)widx;
      unsigned wl = widx & 63u, wj = widx >> 6;
      unsigned g = wj >> 3, jj = wj & 7u;
      bool isw = (lane == (int)wl);
      switch (g) {
        case 0: KNN_REB(0); break;
        case 1: KNN_REB(1); break;
        case 2: KNN_REB(2); break;
        case 3: KNN_REB(3); break;
        case 4: KNN_REB(4); break;
        case 5: KNN_REB(5); break;
        case 6: KNN_REB(6); break;
        default: KNN_REB(7); break;
      }
    }
  }
}

// ---------------------------------------------------------------------------
// MLP: 3 recompute stages (stage 3 writes pre-BN max over K; gamma>0 makes
// BN+ReLU monotone) + tiny elementwise BN kernel. wb = 128*72 -> ~48 KB LDS
// -> 3 blocks/CU.
// ---------------------------------------------------------------------------
template<int KS, int NT>
__device__ __forceinline__ void layer_mfma(const unsigned short* A, const unsigned short* W,
                                           int wstride, f32x4 (&acc)[2][NT], int wave, int lane)
{
  const int quad = lane >> 4, row0 = lane & 15;
  bf16x8 a[2][KS];
#pragma unroll
  for (int m2 = 0; m2 < 2; ++m2)
#pragma unroll
    for (int ks = 0; ks < KS; ++ks)
      a[m2][ks] = *(const bf16x8*)&A[((wave*2+m2)*16 + row0)*104 + ks*32 + quad*8];
#pragma unroll
  for (int m2 = 0; m2 < 2; ++m2)
#pragma unroll
    for (int n = 0; n < NT; ++n)
      acc[m2][n] = (f32x4){0.f,0.f,0.f,0.f};
#pragma unroll
  for (int n = 0; n < NT; ++n) {
#pragma unroll
    for (int ks = 0; ks < KS; ++ks) {
      bf16x8 bfrag = *(const bf16x8*)&W[(n*16 + row0)*wstride + ks*32 + quad*8];
      acc[0][n] = mfma_16x16x32(a[0][ks], bfrag, acc[0][n]);
      acc[1][n] = mfma_16x16x32(a[1][ks], bfrag, acc[1][n]);
    }
  }
}

template<int NT>
__device__ __forceinline__ void stats_ep(const f32x4 (&acc)[2][NT], float* sum, float* sq, int lane)
{
  const int part = blockIdx.x & 63;
  const int col0 = lane & 15;
#pragma unroll
  for (int n = 0; n < NT; ++n) {
    float s = 0.f, q = 0.f;
#pragma unroll
    for (int m2 = 0; m2 < 2; ++m2)
#pragma unroll
      for (int t = 0; t < 4; ++t) { float z = acc[m2][n][t]; s += z; q += z*z; }
    s += __shfl_xor(s, 16, 64); q += __shfl_xor(q, 16, 64);
    s += __shfl_xor(s, 32, 64); q += __shfl_xor(q, 32, 64);
    if (lane < 16) {
      atomicAdd(&sum[part*128 + n*16 + col0], s);
      atomicAdd(&sq [part*128 + n*16 + col0], q);
    }
  }
}

template<int NT>
__device__ __forceinline__ void bn_store(const f32x4 (&acc)[2][NT], unsigned short* A,
                                         const float* lmu, const float* lrsg, const float* lbeta,
                                         int off, int wave, int quad, int col0)
{
#pragma unroll
  for (int n = 0; n < NT; ++n) {
    int c = n*16 + col0;
    float mu = lmu[off+c], rg = lrsg[off+c], bt = lbeta[off+c];
#pragma unroll
    for (int m2 = 0; m2 < 2; ++m2)
#pragma unroll
      for (int t = 0; t < 4; ++t) {
        int row = (wave*2+m2)*16 + quad*4 + t;
        float v = fmaxf((acc[m2][n][t] - mu)*rg + bt, 0.0f);
        A[row*104 + c] = f2bf(v);
      }
  }
}

__device__ __forceinline__ void gather_tile(const float* xyz, const float* pts,
                                            const float* newxyz, const int* knn,
                                            unsigned short* sA, int tid)
{
  const int r = tid >> 1, half = tid & 1;
  const int ql = r >> 5, kk = r & 31;
  const int fq = blockIdx.x*4 + ql;
  const int b  = fq >> 10;
  const int p  = knn[(size_t)fq*K_ + kk];
  const float4* p4 = (const float4*)(pts + ((size_t)(b<<12) + p) * CPTS);
  ushort8* arow = (ushort8*)&sA[r*104];
  if (half == 0) {
#pragma unroll
    for (int ch = 0; ch < 4; ++ch) {
      float4 a = p4[ch*2], bq = p4[ch*2+1];
      ushort8 v = { f2bf(a.x),f2bf(a.y),f2bf(a.z),f2bf(a.w),
                    f2bf(bq.x),f2bf(bq.y),f2bf(bq.z),f2bf(bq.w) };
      arow[ch] = v;
    }
  } else {
#pragma unroll
    for (int ch = 4; ch < 8; ++ch) {
      float4 a = p4[ch*2], bq = p4[ch*2+1];
      ushort8 v = { f2bf(a.x),f2bf(a.y),f2bf(a.z),f2bf(a.w),
                    f2bf(bq.x),f2bf(bq.y),f2bf(bq.z),f2bf(bq.w) };
      arow[ch] = v;
    }
    const float* xr = xyz + ((size_t)(b<<12) + p)*3;
    float qx = newxyz[fq*3+0], qy = newxyz[fq*3+1], qz = newxyz[fq*3+2];
    ushort8 vx = { f2bf(fsub_(xr[0],qx)), f2bf(fsub_(xr[1],qy)), f2bf(fsub_(xr[2],qz)),
                   0,0,0,0,0 };
    arow[8] = vx;
    ushort8 z = {0,0,0,0,0,0,0,0};
    arow[9] = z; arow[10] = z; arow[11] = z;
  }
}

__device__ __forceinline__ void load_w0(const float* W0, unsigned short* wb, int tid)
{
  const int n = tid >> 2, q = tid & 3;
  const float* wr = W0 + n*67;
#pragma unroll
  for (int ch = 0; ch < 3; ++ch) {
    int c0 = q*24 + ch*8;
    ushort8 v;
#pragma unroll
    for (int j = 0; j < 8; ++j) {
      int cc = c0 + j;
      float f = (cc < 64) ? wr[3+cc] : ((cc < 67) ? wr[cc-64] : 0.0f);
      v[j] = f2bf(f);
    }
    *(ushort8*)&wb[n*104 + c0] = v;
  }
}

__device__ __forceinline__ void load_w1(const float* W1, unsigned short* wb, int tid)
{
  const int n = tid >> 2, k0 = (tid & 3) * 16;
  const float4* w4 = (const float4*)(W1 + n*64 + k0);
#pragma unroll
  for (int i = 0; i < 2; ++i) {
    float4 a = w4[i*2], bq = w4[i*2+1];
    ushort8 v = { f2bf(a.x),f2bf(a.y),f2bf(a.z),f2bf(a.w),
                  f2bf(bq.x),f2bf(bq.y),f2bf(bq.z),f2bf(bq.w) };
    ((ushort8*)&wb[n*72 + k0])[i] = v;
  }
}

__device__ __forceinline__ void load_w2(const float* W2, unsigned short* wb, int tid)
{
  const int n = tid >> 1, k0 = (tid & 1) * 32;
  const float4* w4 = (const float4*)(W2 + n*64 + k0);
#pragma unroll
  for (int i = 0; i < 4; ++i) {
    float4 a = w4[i*2], bq = w4[i*2+1];
    ushort8 v = { f2bf(a.x),f2bf(a.y),f2bf(a.z),f2bf(a.w),
                  f2bf(bq.x),f2bf(bq.y),f2bf(bq.z),f2bf(bq.w) };
    ((ushort8*)&wb[n*72 + k0])[i] = v;
  }
}

template<int STAGE>
__global__ __launch_bounds__(256) void mlp_kernel(
    const float* __restrict__ xyz, const float* __restrict__ pts,
    const float* __restrict__ W0, const float* __restrict__ g0, const float* __restrict__ be0,
    const float* __restrict__ W1, const float* __restrict__ g1, const float* __restrict__ be1,
    const float* __restrict__ W2, const float* __restrict__ g2, const float* __restrict__ be2,
    const float* __restrict__ newxyz, const int* __restrict__ knn,
    float* __restrict__ stats, float* __restrict__ out1)
{
  __shared__ unsigned short sA[128*104];   // 26624 B
  __shared__ unsigned short wb[128*72];    // 18432 B (W0 stride-104: 64 rows fit)
  __shared__ float lmu[256], lrsg[256], lbeta[256];

  const int tid  = threadIdx.x;
  const int wave = tid >> 6, lane = tid & 63;
  const int quad = lane >> 4, col0 = lane & 15;

  {
    const int nl = STAGE - 1;
    const int   couts[3] = {64,64,128};
    const int   offs[3]  = {0,64,128};
    const float* gs[3]   = {g0,g1,g2};
    const float* bs[3]   = {be0,be1,be2};
    for (int l = 0; l < nl; ++l) {
      if (tid < couts[l]) {
        const float* su = stats + (size_t)(2*l)*8192;
        const float* sq = stats + (size_t)(2*l+1)*8192;
        float sm = 0.f, q = 0.f;
        for (int p = 0; p < 64; ++p) { sm += su[p*128+tid]; q += sq[p*128+tid]; }
        float mu  = sm * (1.0f/524288.0f);
        float var = q  * (1.0f/524288.0f) - mu*mu;
        float rs  = rsqrtf(var + 1e-5f);
        lmu [offs[l]+tid] = mu;
        lrsg[offs[l]+tid] = rs * gs[l][tid];
        lbeta[offs[l]+tid] = bs[l][tid];
      }
    }
  }

  gather_tile(xyz, pts, newxyz, knn, sA, tid);
  load_w0(W0, wb, tid);
  __syncthreads();

  f32x4 acc0[2][4];
  layer_mfma<3,4>(sA, wb, 104, acc0, wave, lane);
  if constexpr (STAGE == 1) { stats_ep<4>(acc0, stats + 0*8192, stats + 1*8192, lane); return; }
  __syncthreads();

  bn_store<4>(acc0, sA, lmu, lrsg, lbeta, 0, wave, quad, col0);
  load_w1(W1, wb, tid);
  __syncthreads();

  f32x4 acc1[2][4];
  layer_mfma<2,4>(sA, wb, 72, acc1, wave, lane);
  if constexpr (STAGE == 2) { stats_ep<4>(acc1, stats + 2*8192, stats + 3*8192, lane); return; }
  __syncthreads();

  bn_store<4>(acc1, sA, lmu, lrsg, lbeta, 64, wave, quad, col0);
  load_w2(W2, wb, tid);
  __syncthreads();

  f32x4 acc2[2][8];
  layer_mfma<2,8>(sA, wb, 72, acc2, wave, lane);
  // STAGE 3: layer-2 stats + pre-BN max over K (gamma>0 => BN+ReLU monotone,
  // so max commutes with the affine; BN applied later by mlpE_kernel).
  stats_ep<8>(acc2, stats + 4*8192, stats + 5*8192, lane);
  {
    const int fq = blockIdx.x*4 + wave;   // wave == query within tile
#pragma unroll
    for (int n = 0; n < 8; ++n) {
      int c = n*16 + col0;
      float mx = -INFINITY;
#pragma unroll
      for (int m2 = 0; m2 < 2; ++m2)
#pragma unroll
        for (int t = 0; t < 4; ++t)
          mx = fmaxf(mx, acc2[m2][n][t]);
      mx = fmaxf(mx, __shfl_xor(mx, 16, 64));
      mx = fmaxf(mx, __shfl_xor(mx, 32, 64));
      if (lane < 16) out1[(size_t)fq*128 + c] = mx;
    }
  }
}

// elementwise: out1 = relu((out1 - mu2)*rsg2 + beta2), 2M elems
__global__ __launch_bounds__(256) void mlpE_kernel(
    const float* __restrict__ g2, const float* __restrict__ be2,
    const float* __restrict__ stats, float* __restrict__ out1)
{
  __shared__ float lmu[128], lrsg[128], lbeta[128];
  const int tid = threadIdx.x;
  if (tid < 128) {
    const float* su = stats + (size_t)4*8192;
    const float* sq = stats + (size_t)5*8192;
    float sm = 0.f, q = 0.f;
    for (int p = 0; p < 64; ++p) { sm += su[p*128+tid]; q += sq[p*128+tid]; }
    float mu  = sm * (1.0f/524288.0f);
    float var = q  * (1.0f/524288.0f) - mu*mu;
    float rs  = rsqrtf(var + 1e-5f);
    lmu[tid]  = mu;
    lrsg[tid] = rs * g2[tid];
    lbeta[tid]= be2[tid];
  }
  __syncthreads();

  const size_t base = (size_t)blockIdx.x*1024 + tid*4;   // 4 consecutive, same row
  const int c0 = (int)(base & 127);
  float4 v = *(float4*)(out1 + base);
  v.x = fmaxf((v.x - lmu[c0+0])*lrsg[c0+0] + lbeta[c0+0], 0.0f);
  v.y = fmaxf((v.y - lmu[c0+1])*lrsg[c0+1] + lbeta[c0+1], 0.0f);
  v.z = fmaxf((v.z - lmu[c0+2])*lrsg[c0+2] + lbeta[c0+2], 0.0f);
  v.w = fmaxf((v.w - lmu[c0+3])*lrsg[c0+3] + lbeta[c0+3], 0.0f);
  *(float4*)(out1 + base) = v;
}

// ---------------------------------------------------------------------------
extern "C" void kernel_launch(void* const* d_in, const int* in_sizes, int n_in,
                              void* d_out, int out_size, void* d_ws, size_t ws_size,
                              hipStream_t stream)
{
  (void)in_sizes; (void)n_in; (void)out_size; (void)ws_size;
  const float* xyz  = (const float*)d_in[0];
  const float* pts  = (const float*)d_in[1];
  const float* W0   = (const float*)d_in[2];
  const float* g0   = (const float*)d_in[3];
  const float* be0  = (const float*)d_in[4];
  const float* W1   = (const float*)d_in[5];
  const float* g1   = (const float*)d_in[6];
  const float* be1  = (const float*)d_in[7];
  const float* W2   = (const float*)d_in[8];
  const float* g2   = (const float*)d_in[9];
  const float* be2  = (const float*)d_in[10];

  float* out  = (float*)d_out;                   // new_xyz: 16*1024*3
  float* out1 = out + (size_t)B_*S_*3;           // features: 16*1024*128
  int*   knn   = (int*)d_ws;                                     // 2 MB
  float* stats = (float*)((char*)d_ws + (size_t)B_*S_*K_*4);     // 6*8192 floats

  fps_kernel<<<16, 256, 0, stream>>>(xyz, out, stats);
  knn_kernel<<<1024, 256, 0, stream>>>(xyz, out, knn);
  mlp_kernel<1><<<4096, 256, 0, stream>>>(xyz, pts, W0,g0,be0, W1,g1,be1, W2,g2,be2, out, knn, stats, out1);
  mlp_kernel<2><<<4096, 256, 0, stream>>>(xyz, pts, W0,g0,be0, W1,g1,be1, W2,g2,be2, out, knn, stats, out1);
  mlp_kernel<3><<<4096, 256, 0, stream>>>(xyz, pts, W0,g0,be0, W1,g1,be1, W2,g2,be2, out, knn, stats, out1);
  mlpE_kernel<<<2048, 256, 0, stream>>>(g2, be2, stats, out1);
}

// Round 14
// 1196.655 us; speedup vs baseline: 1.0697x; 1.0697x over previous
//
#include <hip/hip_runtime.h>
#include <stdint.h>

#define B_    16
#define N_    4096
#define CPTS  64
#define S_    1024
#define K_    32

typedef __bf16 bf16x8 __attribute__((ext_vector_type(8)));
typedef float  f32x4  __attribute__((ext_vector_type(4)));
typedef unsigned short ushort8 __attribute__((ext_vector_type(8)));

__device__ __forceinline__ float fmul_(float a, float b){ return __fmul_rn(a,b); }
__device__ __forceinline__ float fadd_(float a, float b){ return __fadd_rn(a,b); }
__device__ __forceinline__ float fsub_(float a, float b){ return __fsub_rn(a,b); }

__device__ __forceinline__ unsigned short f2bf(float f){
  unsigned u = __float_as_uint(f);
  unsigned r = (u + 0x7FFFu + ((u >> 16) & 1u)) >> 16;
  return (unsigned short)r;
}

__device__ __forceinline__ f32x4 mfma_16x16x32(bf16x8 a, bf16x8 b, f32x4 c){
  return __builtin_amdgcn_mfma_f32_16x16x32_bf16(a, b, c, 0, 0, 0);
}

__device__ __forceinline__ unsigned long long umin64(unsigned long long a, unsigned long long b){
  return b < a ? b : a;
}
__device__ __forceinline__ unsigned long long umax64(unsigned long long a, unsigned long long b){
  return a < b ? b : a;
}

template<int CTRL>
__device__ __forceinline__ unsigned dppmove(unsigned v){
  return (unsigned)__builtin_amdgcn_update_dpp((int)v, (int)v, CTRL, 0xF, 0xF, false);
}
__device__ __forceinline__ unsigned wave_umax_dpp(unsigned v){
  unsigned t;
  t = dppmove<0x111>(v); v = v > t ? v : t;
  t = dppmove<0x112>(v); v = v > t ? v : t;
  t = dppmove<0x114>(v); v = v > t ? v : t;
  t = dppmove<0x118>(v); v = v > t ? v : t;
  t = dppmove<0x142>(v); v = v > t ? v : t;
  t = dppmove<0x143>(v); v = v > t ? v : t;
  return (unsigned)__builtin_amdgcn_readlane((int)v, 63);
}
__device__ __forceinline__ unsigned wave_umin_dpp(unsigned v){
  unsigned t;
  t = dppmove<0x111>(v); v = v < t ? v : t;
  t = dppmove<0x112>(v); v = v < t ? v : t;
  t = dppmove<0x114>(v); v = v < t ? v : t;
  t = dppmove<0x118>(v); v = v < t ? v : t;
  t = dppmove<0x142>(v); v = v < t ? v : t;
  t = dppmove<0x143>(v); v = v < t ? v : t;
  return (unsigned)__builtin_amdgcn_readlane((int)v, 63);
}

// ---------------------------------------------------------------------------
// FPS (round-10 proven local optimum, 88 VGPR — structure frozen after 7
// experiments; barrier+reduce latency dominated, all restructures regressed):
// one block per batch, 256 threads, 16 pts/thread in registers.
// ---------------------------------------------------------------------------
__global__ __launch_bounds__(256) void fps_kernel(const float* __restrict__ xyz,
                                                  float* __restrict__ out_newxyz,
                                                  float* __restrict__ stats)
{
  const int b   = blockIdx.x;
  const int tid = threadIdx.x;
  const int wave = tid >> 6;
  __shared__ float4 lp[N_];
  __shared__ unsigned long long wc[2][4];
  __shared__ int fhist[S_ + 1];

  // zero stats: 6*8192 floats = 12288 float4, 16 blocks x 256 thr x 3 each
  {
    float4* s4 = (float4*)stats;
    const int base = (b*256 + tid)*3;
    const float4 z = make_float4(0.f,0.f,0.f,0.f);
    s4[base+0] = z; s4[base+1] = z; s4[base+2] = z;
  }

  const float* xb = xyz + (size_t)b * (N_*3);
  float px[16], py[16], pz[16], dmin[16];
#pragma unroll
  for (int i = 0; i < 16; ++i) {
    int n = i*256 + tid;
    float x = xb[n*3+0], y = xb[n*3+1], z = xb[n*3+2];
    lp[n] = make_float4(x,y,z,0.0f);
    px[i]=x; py[i]=y; pz[i]=z;
    dmin[i] = INFINITY;
  }
  if (tid == 0) fhist[0] = 0;
  __syncthreads();

  int far = 0;
  for (int step = 0; step < S_; ++step) {
    float4 cp = lp[far];
    float cx = cp.x, cy = cp.y, cz = cp.z;
    float bv = -1.0f; unsigned bidx = 0;
#pragma unroll
    for (int i = 0; i < 16; ++i) {
      float dx = fsub_(px[i],cx), dy = fsub_(py[i],cy), dz = fsub_(pz[i],cz);
      float d  = fadd_(fadd_(fmul_(dx,dx),fmul_(dy,dy)),fmul_(dz,dz));
      float dm = fminf(dmin[i], d);
      dmin[i] = dm;
      bool gt = dm > bv;
      bv   = gt ? dm : bv;
      bidx = gt ? (unsigned)(i*256 + tid) : bidx;
    }
    unsigned bvb  = __float_as_uint(bv);
    unsigned wmax = wave_umax_dpp(bvb);
    unsigned cand = (bvb == wmax) ? ~bidx : 0u;
    unsigned winv = wave_umax_dpp(cand);
    unsigned long long kv = ((unsigned long long)wmax << 32) | winv;

    int par = step & 1;
    if ((tid & 63) == 0) wc[par][wave] = kv;
    __syncthreads();
    unsigned long long b0 = umax64(wc[par][0], wc[par][1]);
    unsigned long long b1 = umax64(wc[par][2], wc[par][3]);
    far = (int)(~(unsigned)umax64(b0, b1));
    if (tid == 0) fhist[step + 1] = far;
  }
  __syncthreads();

  float* ob = out_newxyz + (size_t)b*S_*3;
#pragma unroll
  for (int j = 0; j < 4; ++j) {
    int s = j*256 + tid;
    float4 p = lp[fhist[s]];
    ob[s*3+0] = p.x; ob[s*3+1] = p.y; ob[s*3+2] = p.z;
  }
}

// ---------------------------------------------------------------------------
// kNN (round-8): wave-per-query, all-VALU extraction (DPP two-phase min).
// ---------------------------------------------------------------------------
#define KNN_REB(G) { \
  if (isw) { \
    if      (jj==0u) sk[(G)*8+0]=0xFFFFFFFFu; else if (jj==1u) sk[(G)*8+1]=0xFFFFFFFFu; \
    else if (jj==2u) sk[(G)*8+2]=0xFFFFFFFFu; else if (jj==3u) sk[(G)*8+3]=0xFFFFFFFFu; \
    else if (jj==4u) sk[(G)*8+4]=0xFFFFFFFFu; else if (jj==5u) sk[(G)*8+5]=0xFFFFFFFFu; \
    else if (jj==6u) sk[(G)*8+6]=0xFFFFFFFFu; else              sk[(G)*8+7]=0xFFFFFFFFu; } \
  { unsigned bk = sk[(G)*8+0]; unsigned bi = (unsigned)(((G)*8+0)*64 + lane); \
    _Pragma("unroll") \
    for (int j2 = 1; j2 < 8; ++j2) { \
      unsigned k2 = sk[(G)*8+j2]; unsigned i2 = (unsigned)(((G)*8+j2)*64 + lane); \
      bool lt = k2 < bk; bk = lt ? k2 : bk; bi = lt ? i2 : bi; } \
    gk[(G)] = bk; gi[(G)] = bi; } }

__global__ __launch_bounds__(256) void knn_kernel(const float* __restrict__ xyz,
                                                  const float* __restrict__ newxyz,
                                                  int* __restrict__ knn)
{
  __shared__ float4 lp[N_];
  const int b     = blockIdx.x >> 6;
  const int chunk = blockIdx.x & 63;
  const float* xb = xyz + (size_t)b * (N_*3);
  for (int e = threadIdx.x; e < N_; e += 256) {
    float x = xb[e*3+0], y = xb[e*3+1], z = xb[e*3+2];
    float d2 = fadd_(fadd_(fmul_(x,x),fmul_(y,y)),fmul_(z,z));
    lp[e] = make_float4(x,y,z,d2);
  }
  __syncthreads();

  const int wave = threadIdx.x >> 6, lane = threadIdx.x & 63;
  for (int qi = 0; qi < 4; ++qi) {
    const int s  = chunk*16 + wave*4 + qi;
    const int fq = b*S_ + s;
    float qx = newxyz[fq*3+0], qy = newxyz[fq*3+1], qz = newxyz[fq*3+2];
    float s2 = fadd_(fadd_(fmul_(qx,qx),fmul_(qy,qy)),fmul_(qz,qz));

    unsigned sk[64];
#pragma unroll
    for (int j = 0; j < 64; ++j) {
      float4 p = lp[j*64 + lane];
      float dot = fadd_(fadd_(fmul_(qx,p.x),fmul_(qy,p.y)),fmul_(qz,p.z));
      float d   = fadd_(fsub_(s2, fmul_(2.0f,dot)), p.w);
      unsigned u = __float_as_uint(d);
      sk[j] = u ^ ((unsigned)((int)u >> 31) | 0x80000000u);
    }
    unsigned gk[8], gi[8];
#pragma unroll
    for (int g = 0; g < 8; ++g) {
      unsigned bk = sk[g*8+0], bi = (unsigned)((g*8+0)*64 + lane);
#pragma unroll
      for (int j = 1; j < 8; ++j) {
        unsigned k2 = sk[g*8+j]; unsigned i2 = (unsigned)((g*8+j)*64 + lane);
        bool lt = k2 < bk; bk = lt ? k2 : bk; bi = lt ? i2 : bi;
      }
      gk[g]=bk; gi[g]=bi;
    }
    int* ko = knn + (size_t)fq * K_;
    for (int it = 0; it < K_; ++it) {
      unsigned long long c0 = ((unsigned long long)gk[0] << 32) | gi[0];
      unsigned long long c1 = ((unsigned long long)gk[1] << 32) | gi[1];
      unsigned long long c2 = ((unsigned long long)gk[2] << 32) | gi[2];
      unsigned long long c3 = ((unsigned long long)gk[3] << 32) | gi[3];
      unsigned long long c4 = ((unsigned long long)gk[4] << 32) | gi[4];
      unsigned long long c5 = ((unsigned long long)gk[5] << 32) | gi[5];
      unsigned long long c6 = ((unsigned long long)gk[6] << 32) | gi[6];
      unsigned long long c7 = ((unsigned long long)gk[7] << 32) | gi[7];
      c0 = umin64(c0,c1); c2 = umin64(c2,c3); c4 = umin64(c4,c5); c6 = umin64(c6,c7);
      c0 = umin64(c0,c2); c4 = umin64(c4,c6);
      unsigned long long cand = umin64(c0,c4);
      unsigned lkey = (unsigned)(cand >> 32);
      unsigned lidx = (unsigned)cand;
      unsigned wkey = wave_umin_dpp(lkey);
      unsigned widx = wave_umin_dpp((lkey == wkey) ? lidx : 0xFFFFFFFFu);
      if (lane == 0) ko[it] = (int)widx;
      unsigned wl = widx & 63u, wj = widx >> 6;
      unsigned g = wj >> 3, jj = wj & 7u;
      bool isw = (lane == (int)wl);
      switch (g) {
        case 0: KNN_REB(0); break;
        case 1: KNN_REB(1); break;
        case 2: KNN_REB(2); break;
        case 3: KNN_REB(3); break;
        case 4: KNN_REB(4); break;
        case 5: KNN_REB(5); break;
        case 6: KNN_REB(6); break;
        default: KNN_REB(7); break;
      }
    }
  }
}

// ---------------------------------------------------------------------------
// MLP: 3 recompute stages (stage 3 writes pre-BN max over K; gamma>0 makes
// BN+ReLU monotone) + tiny elementwise BN kernel. wb = 128*72 -> ~48 KB LDS
// -> 3 blocks/CU. NEW: XCD-aware block swizzle bt = (blk&15)*256 + (blk>>4)
// pins each batch's tiles to one XCD (batch%8) so pts gathers stay L2-hot
// (2 MB of pts per XCD instead of 16 MB thrash). Bijective: speed-only.
// ---------------------------------------------------------------------------
template<int KS, int NT>
__device__ __forceinline__ void layer_mfma(const unsigned short* A, const unsigned short* W,
                                           int wstride, f32x4 (&acc)[2][NT], int wave, int lane)
{
  const int quad = lane >> 4, row0 = lane & 15;
  bf16x8 a[2][KS];
#pragma unroll
  for (int m2 = 0; m2 < 2; ++m2)
#pragma unroll
    for (int ks = 0; ks < KS; ++ks)
      a[m2][ks] = *(const bf16x8*)&A[((wave*2+m2)*16 + row0)*104 + ks*32 + quad*8];
#pragma unroll
  for (int m2 = 0; m2 < 2; ++m2)
#pragma unroll
    for (int n = 0; n < NT; ++n)
      acc[m2][n] = (f32x4){0.f,0.f,0.f,0.f};
#pragma unroll
  for (int n = 0; n < NT; ++n) {
#pragma unroll
    for (int ks = 0; ks < KS; ++ks) {
      bf16x8 bfrag = *(const bf16x8*)&W[(n*16 + row0)*wstride + ks*32 + quad*8];
      acc[0][n] = mfma_16x16x32(a[0][ks], bfrag, acc[0][n]);
      acc[1][n] = mfma_16x16x32(a[1][ks], bfrag, acc[1][n]);
    }
  }
}

template<int NT>
__device__ __forceinline__ void stats_ep(const f32x4 (&acc)[2][NT], float* sum, float* sq, int lane)
{
  const int part = blockIdx.x & 63;   // dispatch-order keyed: keeps atomics spread
  const int col0 = lane & 15;
#pragma unroll
  for (int n = 0; n < NT; ++n) {
    float s = 0.f, q = 0.f;
#pragma unroll
    for (int m2 = 0; m2 < 2; ++m2)
#pragma unroll
      for (int t = 0; t < 4; ++t) { float z = acc[m2][n][t]; s += z; q += z*z; }
    s += __shfl_xor(s, 16, 64); q += __shfl_xor(q, 16, 64);
    s += __shfl_xor(s, 32, 64); q += __shfl_xor(q, 32, 64);
    if (lane < 16) {
      atomicAdd(&sum[part*128 + n*16 + col0], s);
      atomicAdd(&sq [part*128 + n*16 + col0], q);
    }
  }
}

template<int NT>
__device__ __forceinline__ void bn_store(const f32x4 (&acc)[2][NT], unsigned short* A,
                                         const float* lmu, const float* lrsg, const float* lbeta,
                                         int off, int wave, int quad, int col0)
{
#pragma unroll
  for (int n = 0; n < NT; ++n) {
    int c = n*16 + col0;
    float mu = lmu[off+c], rg = lrsg[off+c], bt = lbeta[off+c];
#pragma unroll
    for (int m2 = 0; m2 < 2; ++m2)
#pragma unroll
      for (int t = 0; t < 4; ++t) {
        int row = (wave*2+m2)*16 + quad*4 + t;
        float v = fmaxf((acc[m2][n][t] - mu)*rg + bt, 0.0f);
        A[row*104 + c] = f2bf(v);
      }
  }
}

__device__ __forceinline__ void gather_tile(const float* xyz, const float* pts,
                                            const float* newxyz, const int* knn,
                                            unsigned short* sA, int tid, int bt)
{
  const int r = tid >> 1, half = tid & 1;
  const int ql = r >> 5, kk = r & 31;
  const int fq = bt*4 + ql;
  const int b  = fq >> 10;
  const int p  = knn[(size_t)fq*K_ + kk];
  const float4* p4 = (const float4*)(pts + ((size_t)(b<<12) + p) * CPTS);
  ushort8* arow = (ushort8*)&sA[r*104];
  if (half == 0) {
#pragma unroll
    for (int ch = 0; ch < 4; ++ch) {
      float4 a = p4[ch*2], bq = p4[ch*2+1];
      ushort8 v = { f2bf(a.x),f2bf(a.y),f2bf(a.z),f2bf(a.w),
                    f2bf(bq.x),f2bf(bq.y),f2bf(bq.z),f2bf(bq.w) };
      arow[ch] = v;
    }
  } else {
#pragma unroll
    for (int ch = 4; ch < 8; ++ch) {
      float4 a = p4[ch*2], bq = p4[ch*2+1];
      ushort8 v = { f2bf(a.x),f2bf(a.y),f2bf(a.z),f2bf(a.w),
                    f2bf(bq.x),f2bf(bq.y),f2bf(bq.z),f2bf(bq.w) };
      arow[ch] = v;
    }
    const float* xr = xyz + ((size_t)(b<<12) + p)*3;
    float qx = newxyz[fq*3+0], qy = newxyz[fq*3+1], qz = newxyz[fq*3+2];
    ushort8 vx = { f2bf(fsub_(xr[0],qx)), f2bf(fsub_(xr[1],qy)), f2bf(fsub_(xr[2],qz)),
                   0,0,0,0,0 };
    arow[8] = vx;
    ushort8 z = {0,0,0,0,0,0,0,0};
    arow[9] = z; arow[10] = z; arow[11] = z;
  }
}

__device__ __forceinline__ void load_w0(const float* W0, unsigned short* wb, int tid)
{
  const int n = tid >> 2, q = tid & 3;
  const float* wr = W0 + n*67;
#pragma unroll
  for (int ch = 0; ch < 3; ++ch) {
    int c0 = q*24 + ch*8;
    ushort8 v;
#pragma unroll
    for (int j = 0; j < 8; ++j) {
      int cc = c0 + j;
      float f = (cc < 64) ? wr[3+cc] : ((cc < 67) ? wr[cc-64] : 0.0f);
      v[j] = f2bf(f);
    }
    *(ushort8*)&wb[n*104 + c0] = v;
  }
}

__device__ __forceinline__ void load_w1(const float* W1, unsigned short* wb, int tid)
{
  const int n = tid >> 2, k0 = (tid & 3) * 16;
  const float4* w4 = (const float4*)(W1 + n*64 + k0);
#pragma unroll
  for (int i = 0; i < 2; ++i) {
    float4 a = w4[i*2], bq = w4[i*2+1];
    ushort8 v = { f2bf(a.x),f2bf(a.y),f2bf(a.z),f2bf(a.w),
                  f2bf(bq.x),f2bf(bq.y),f2bf(bq.z),f2bf(bq.w) };
    ((ushort8*)&wb[n*72 + k0])[i] = v;
  }
}

__device__ __forceinline__ void load_w2(const float* W2, unsigned short* wb, int tid)
{
  const int n = tid >> 1, k0 = (tid & 1) * 32;
  const float4* w4 = (const float4*)(W2 + n*64 + k0);
#pragma unroll
  for (int i = 0; i < 4; ++i) {
    float4 a = w4[i*2], bq = w4[i*2+1];
    ushort8 v = { f2bf(a.x),f2bf(a.y),f2bf(a.z),f2bf(a.w),
                  f2bf(bq.x),f2bf(bq.y),f2bf(bq.z),f2bf(bq.w) };
    ((ushort8*)&wb[n*72 + k0])[i] = v;
  }
}

template<int STAGE>
__global__ __launch_bounds__(256) void mlp_kernel(
    const float* __restrict__ xyz, const float* __restrict__ pts,
    const float* __restrict__ W0, const float* __restrict__ g0, const float* __restrict__ be0,
    const float* __restrict__ W1, const float* __restrict__ g1, const float* __restrict__ be1,
    const float* __restrict__ W2, const float* __restrict__ g2, const float* __restrict__ be2,
    const float* __restrict__ newxyz, const int* __restrict__ knn,
    float* __restrict__ stats, float* __restrict__ out1)
{
  __shared__ unsigned short sA[128*104];   // 26624 B
  __shared__ unsigned short wb[128*72];    // 18432 B (W0 stride-104: 64 rows fit)
  __shared__ float lmu[256], lrsg[256], lbeta[256];

  const int tid  = threadIdx.x;
  const int wave = tid >> 6, lane = tid & 63;
  const int quad = lane >> 4, col0 = lane & 15;
  // XCD-aware swizzle: tiles of batch k land on XCD k%8 (dispatch round-robin)
  const int bt = (blockIdx.x & 15)*256 + (blockIdx.x >> 4);

  {
    const int nl = STAGE - 1;
    const int   couts[3] = {64,64,128};
    const int   offs[3]  = {0,64,128};
    const float* gs[3]   = {g0,g1,g2};
    const float* bs[3]   = {be0,be1,be2};
    for (int l = 0; l < nl; ++l) {
      if (tid < couts[l]) {
        const float* su = stats + (size_t)(2*l)*8192;
        const float* sq = stats + (size_t)(2*l+1)*8192;
        float sm = 0.f, q = 0.f;
        for (int p = 0; p < 64; ++p) { sm += su[p*128+tid]; q += sq[p*128+tid]; }
        float mu  = sm * (1.0f/524288.0f);
        float var = q  * (1.0f/524288.0f) - mu*mu;
        float rs  = rsqrtf(var + 1e-5f);
        lmu [offs[l]+tid] = mu;
        lrsg[offs[l]+tid] = rs * gs[l][tid];
        lbeta[offs[l]+tid] = bs[l][tid];
      }
    }
  }

  gather_tile(xyz, pts, newxyz, knn, sA, tid, bt);
  load_w0(W0, wb, tid);
  __syncthreads();

  f32x4 acc0[2][4];
  layer_mfma<3,4>(sA, wb, 104, acc0, wave, lane);
  if constexpr (STAGE == 1) { stats_ep<4>(acc0, stats + 0*8192, stats + 1*8192, lane); return; }
  __syncthreads();

  bn_store<4>(acc0, sA, lmu, lrsg, lbeta, 0, wave, quad, col0);
  load_w1(W1, wb, tid);
  __syncthreads();

  f32x4 acc1[2][4];
  layer_mfma<2,4>(sA, wb, 72, acc1, wave, lane);
  if constexpr (STAGE == 2) { stats_ep<4>(acc1, stats + 2*8192, stats + 3*8192, lane); return; }
  __syncthreads();

  bn_store<4>(acc1, sA, lmu, lrsg, lbeta, 64, wave, quad, col0);
  load_w2(W2, wb, tid);
  __syncthreads();

  f32x4 acc2[2][8];
  layer_mfma<2,8>(sA, wb, 72, acc2, wave, lane);
  // STAGE 3: layer-2 stats + pre-BN max over K (gamma>0 => BN+ReLU monotone,
  // so max commutes with the affine; BN applied later by mlpE_kernel).
  stats_ep<8>(acc2, stats + 4*8192, stats + 5*8192, lane);
  {
    const int fq = bt*4 + wave;           // wave == query within tile
#pragma unroll
    for (int n = 0; n < 8; ++n) {
      int c = n*16 + col0;
      float mx = -INFINITY;
#pragma unroll
      for (int m2 = 0; m2 < 2; ++m2)
#pragma unroll
        for (int t = 0; t < 4; ++t)
          mx = fmaxf(mx, acc2[m2][n][t]);
      mx = fmaxf(mx, __shfl_xor(mx, 16, 64));
      mx = fmaxf(mx, __shfl_xor(mx, 32, 64));
      if (lane < 16) out1[(size_t)fq*128 + c] = mx;
    }
  }
}

// elementwise: out1 = relu((out1 - mu2)*rsg2 + beta2), 2M elems
__global__ __launch_bounds__(256) void mlpE_kernel(
    const float* __restrict__ g2, const float* __restrict__ be2,
    const float* __restrict__ stats, float* __restrict__ out1)
{
  __shared__ float lmu[128], lrsg[128], lbeta[128];
  const int tid = threadIdx.x;
  if (tid < 128) {
    const float* su = stats + (size_t)4*8192;
    const float* sq = stats + (size_t)5*8192;
    float sm = 0.f, q = 0.f;
    for (int p = 0; p < 64; ++p) { sm += su[p*128+tid]; q += sq[p*128+tid]; }
    float mu  = sm * (1.0f/524288.0f);
    float var = q  * (1.0f/524288.0f) - mu*mu;
    float rs  = rsqrtf(var + 1e-5f);
    lmu[tid]  = mu;
    lrsg[tid] = rs * g2[tid];
    lbeta[tid]= be2[tid];
  }
  __syncthreads();

  const size_t base = (size_t)blockIdx.x*1024 + tid*4;   // 4 consecutive, same row
  const int c0 = (int)(base & 127);
  float4 v = *(float4*)(out1 + base);
  v.x = fmaxf((v.x - lmu[c0+0])*lrsg[c0+0] + lbeta[c0+0], 0.0f);
  v.y = fmaxf((v.y - lmu[c0+1])*lrsg[c0+1] + lbeta[c0+1], 0.0f);
  v.z = fmaxf((v.z - lmu[c0+2])*lrsg[c0+2] + lbeta[c0+2], 0.0f);
  v.w = fmaxf((v.w - lmu[c0+3])*lrsg[c0+3] + lbeta[c0+3], 0.0f);
  *(float4*)(out1 + base) = v;
}

// ---------------------------------------------------------------------------
extern "C" void kernel_launch(void* const* d_in, const int* in_sizes, int n_in,
                              void* d_out, int out_size, void* d_ws, size_t ws_size,
                              hipStream_t stream)
{
  (void)in_sizes; (void)n_in; (void)out_size; (void)ws_size;
  const float* xyz  = (const float*)d_in[0];
  const float* pts  = (const float*)d_in[1];
  const float* W0   = (const float*)d_in[2];
  const float* g0   = (const float*)d_in[3];
  const float* be0  = (const float*)d_in[4];
  const float* W1   = (const float*)d_in[5];
  const float* g1   = (const float*)d_in[6];
  const float* be1  = (const float*)d_in[7];
  const float* W2   = (const float*)d_in[8];
  const float* g2   = (const float*)d_in[9];
  const float* be2  = (const float*)d_in[10];

  float* out  = (float*)d_out;                   // new_xyz: 16*1024*3
  float* out1 = out + (size_t)B_*S_*3;           // features: 16*1024*128
  int*   knn   = (int*)d_ws;                                     // 2 MB
  float* stats = (float*)((char*)d_ws + (size_t)B_*S_*K_*4);     // 6*8192 floats

  fps_kernel<<<16, 256, 0, stream>>>(xyz, out, stats);
  knn_kernel<<<1024, 256, 0, stream>>>(xyz, out, knn);
  mlp_kernel<1><<<4096, 256, 0, stream>>>(xyz, pts, W0,g0,be0, W1,g1,be1, W2,g2,be2, out, knn, stats, out1);
  mlp_kernel<2><<<4096, 256, 0, stream>>>(xyz, pts, W0,g0,be0, W1,g1,be1, W2,g2,be2, out, knn, stats, out1);
  mlp_kernel<3><<<4096, 256, 0, stream>>>(xyz, pts, W0,g0,be0, W1,g1,be1, W2,g2,be2, out, knn, stats, out1);
  mlpE_kernel<<<2048, 256, 0, stream>>>(g2, be2, stats, out1);
}